// Round 1
// baseline (2927.064 us; speedup 1.0000x reference)
//
#include <hip/hip_runtime.h>
#include <hip/hip_bf16.h>

#define DD 128

__device__ __forceinline__ float bf2f(unsigned short u) {
    union { unsigned int v; float f; } x; x.v = ((unsigned int)u) << 16; return x.f;
}
__device__ __forceinline__ unsigned short f2bf(float f) {
    union { float f; unsigned int u; } x; x.f = f;
    unsigned int u = x.u;
    unsigned int r = (u + 0x7FFFu + ((u >> 16) & 1u)) >> 16;  // RNE
    return (unsigned short)r;
}

// C[M x NOUT] = act( A[M x K] @ W[NOUT x K]^T + bias )
// MODE 0: A-load applies PReLU; no bias; epilogue writes Hb (bf16) and Cf = acc + self_emb
// MODE 1: bias + ReLU -> Cf
// MODE 2: bias -> Cf
template<int K, int NOUT, int MODE>
__global__ __launch_bounds__(256) void gemm_k(
    const float* __restrict__ A, const float* __restrict__ W,
    const float* __restrict__ bias, float* __restrict__ Cf,
    unsigned short* __restrict__ Hb,
    const float* __restrict__ emb1, const float* __restrict__ emb2,
    const float* __restrict__ prelu_a, int M)
{
    const int BM = 64, BN = 64, BK = 32;
    __shared__ float As[BK][BM + 4];   // +4 pad keeps rows 16B-aligned, breaks conflicts
    __shared__ float Bs[BK][BN + 4];
    const int bm = blockIdx.x * BM;
    const int bn = blockIdx.y * BN;
    const int tid = threadIdx.x;
    const int tx = tid & 15, ty = tid >> 4;
    float acc[4][4] = {};
    float pa = 0.f;
    if (MODE == 0) pa = prelu_a[0];

    for (int k0 = 0; k0 < K; k0 += BK) {
        // stage A tile (64x32), transposed into As[k][m]
        #pragma unroll
        for (int t = tid; t < BM * BK / 4; t += 256) {
            int m = t >> 3, kq = t & 7;
            int gm = bm + m;
            float4 v = make_float4(0.f, 0.f, 0.f, 0.f);
            if (gm < M) v = *(const float4*)&A[(size_t)gm * K + k0 + kq * 4];
            if (MODE == 0) {
                v.x = v.x >= 0.f ? v.x : pa * v.x;
                v.y = v.y >= 0.f ? v.y : pa * v.y;
                v.z = v.z >= 0.f ? v.z : pa * v.z;
                v.w = v.w >= 0.f ? v.w : pa * v.w;
            }
            As[kq * 4 + 0][m] = v.x; As[kq * 4 + 1][m] = v.y;
            As[kq * 4 + 2][m] = v.z; As[kq * 4 + 3][m] = v.w;
        }
        // stage W tile (64 rows x 32 k), transposed into Bs[k][n]
        #pragma unroll
        for (int t = tid; t < BN * BK / 4; t += 256) {
            int n = t >> 3, kq = t & 7;
            float4 v = *(const float4*)&W[(size_t)(bn + n) * K + k0 + kq * 4];
            Bs[kq * 4 + 0][n] = v.x; Bs[kq * 4 + 1][n] = v.y;
            Bs[kq * 4 + 2][n] = v.z; Bs[kq * 4 + 3][n] = v.w;
        }
        __syncthreads();
        #pragma unroll
        for (int k = 0; k < BK; ++k) {
            float4 a4 = *(const float4*)&As[k][tx * 4];
            float4 b4 = *(const float4*)&Bs[k][ty * 4];
            float av[4] = {a4.x, a4.y, a4.z, a4.w};
            float bv[4] = {b4.x, b4.y, b4.z, b4.w};
            #pragma unroll
            for (int i = 0; i < 4; ++i)
                #pragma unroll
                for (int j = 0; j < 4; ++j)
                    acc[i][j] += av[i] * bv[j];
        }
        __syncthreads();
    }

    const int n0 = bn + ty * 4;
    float se[4];
    if (MODE == 0) {
        #pragma unroll
        for (int j = 0; j < 4; ++j) se[j] = emb1[4 * DD + n0 + j] + emb2[n0 + j];
    }
    #pragma unroll
    for (int i = 0; i < 4; ++i) {
        int gm = bm + tx * 4 + i;
        if (gm >= M) continue;
        if (MODE == 0) {
            ushort4 hb;
            hb.x = f2bf(acc[i][0]); hb.y = f2bf(acc[i][1]);
            hb.z = f2bf(acc[i][2]); hb.w = f2bf(acc[i][3]);
            *(ushort4*)&Hb[(size_t)gm * DD + n0] = hb;
            float4 av = {acc[i][0] + se[0], acc[i][1] + se[1],
                         acc[i][2] + se[2], acc[i][3] + se[3]};
            *(float4*)&Cf[(size_t)gm * NOUT + n0] = av;
        } else {
            float4 v = {acc[i][0] + bias[n0 + 0], acc[i][1] + bias[n0 + 1],
                        acc[i][2] + bias[n0 + 2], acc[i][3] + bias[n0 + 3]};
            if (MODE == 1) {
                v.x = fmaxf(v.x, 0.f); v.y = fmaxf(v.y, 0.f);
                v.z = fmaxf(v.z, 0.f); v.w = fmaxf(v.w, 0.f);
            }
            *(float4*)&Cf[(size_t)gm * NOUT + n0] = v;
        }
    }
}

// agg[dst] += h[src] + emb1[a0] + emb2[a1], 32 lanes/edge, 4 f32 per lane
__global__ __launch_bounds__(256) void scatter_k(
    const unsigned short* __restrict__ h,
    const int* __restrict__ edge_index, const int* __restrict__ edge_attr,
    const float* __restrict__ emb1, const float* __restrict__ emb2,
    float* __restrict__ agg, int E)
{
    int t = blockIdx.x * 256 + threadIdx.x;
    int e = t >> 5;
    int q = t & 31;
    if (e >= E) return;
    int src = edge_index[e];
    int dst = edge_index[E + e];
    int a0 = edge_attr[2 * e];
    int a1 = edge_attr[2 * e + 1];
    ushort4 hv = *(const ushort4*)&h[(size_t)src * DD + q * 4];
    float4 e1 = *(const float4*)&emb1[a0 * DD + q * 4];
    float4 e2 = *(const float4*)&emb2[a1 * DD + q * 4];
    float* ap = agg + (size_t)dst * DD + q * 4;
    unsafeAtomicAdd(ap + 0, bf2f(hv.x) + e1.x + e2.x);
    unsafeAtomicAdd(ap + 1, bf2f(hv.y) + e1.y + e2.y);
    unsafeAtomicAdd(ap + 2, bf2f(hv.z) + e1.z + e2.z);
    unsafeAtomicAdd(ap + 3, bf2f(hv.w) + e1.w + e2.w);
}

extern "C" void kernel_launch(void* const* d_in, const int* in_sizes, int n_in,
                              void* d_out, int out_size, void* d_ws, size_t ws_size,
                              hipStream_t stream) {
    const float* x     = (const float*)d_in[0];
    const int*   ei    = (const int*)d_in[1];
    const int*   ea    = (const int*)d_in[2];
    const float* pa    = (const float*)d_in[3];
    const float* Wenc  = (const float*)d_in[4];
    const float* emb1  = (const float*)d_in[5];
    const float* emb2  = (const float*)d_in[6];
    const float* W1    = (const float*)d_in[7];
    const float* b1    = (const float*)d_in[8];
    const float* W2    = (const float*)d_in[9];
    const float* b2    = (const float*)d_in[10];
    float* out = (float*)d_out;

    const int M = in_sizes[0] / DD;
    const int E = in_sizes[1] / 2;

    char* ws = (char*)d_ws;
    unsigned short* h_bf = (unsigned short*)ws;                                  // M*128 bf16
    float* agg = (float*)(ws + (size_t)M * DD * 2);                              // M*128 f32
    float* hid = (float*)(ws + (size_t)M * DD * 2 + (size_t)M * DD * 4);         // M*256 f32

    const int gm = (M + 63) / 64;
    dim3 blk(256);

    gemm_k<128, 128, 0><<<dim3(gm, 2), blk, 0, stream>>>(
        x, Wenc, nullptr, agg, h_bf, emb1, emb2, pa, M);

    int sb = (E * 32 + 255) / 256;
    scatter_k<<<dim3(sb), blk, 0, stream>>>(h_bf, ei, ea, emb1, emb2, agg, E);

    gemm_k<128, 256, 1><<<dim3(gm, 4), blk, 0, stream>>>(
        agg, W1, b1, hid, nullptr, nullptr, nullptr, nullptr, M);

    gemm_k<256, 128, 2><<<dim3(gm, 2), blk, 0, stream>>>(
        hid, W2, b2, out, nullptr, nullptr, nullptr, nullptr, M);
}

// Round 2
// 737.811 us; speedup vs baseline: 3.9672x; 3.9672x over previous
//
#include <hip/hip_runtime.h>
#include <hip/hip_bf16.h>

#define DD 128

__device__ __forceinline__ float bf2f(unsigned short u) {
    union { unsigned int v; float f; } x; x.v = ((unsigned int)u) << 16; return x.f;
}
__device__ __forceinline__ unsigned short f2bf(float f) {
    union { float f; unsigned int u; } x; x.f = f;
    unsigned int u = x.u;
    unsigned int r = (u + 0x7FFFu + ((u >> 16) & 1u)) >> 16;  // RNE
    return (unsigned short)r;
}

// C[M x NOUT] = act( A[M x K] @ W[NOUT x K]^T + bias )
// MODE 0: A-load applies PReLU; no bias; epilogue writes Hb (bf16) and Cf = acc + self_emb
// MODE 1: bias + ReLU -> Cf
// MODE 2: bias -> Cf
template<int K, int NOUT, int MODE>
__global__ __launch_bounds__(256) void gemm_k(
    const float* __restrict__ A, const float* __restrict__ W,
    const float* __restrict__ bias, float* __restrict__ Cf,
    unsigned short* __restrict__ Hb,
    const float* __restrict__ emb1, const float* __restrict__ emb2,
    const float* __restrict__ prelu_a, int M)
{
    const int BM = 64, BN = 64, BK = 32;
    __shared__ float As[BK][BM + 4];
    __shared__ float Bs[BK][BN + 4];
    const int bm = blockIdx.x * BM;
    const int bn = blockIdx.y * BN;
    const int tid = threadIdx.x;
    const int tx = tid & 15, ty = tid >> 4;
    float acc[4][4] = {};
    float pa = 0.f;
    if (MODE == 0) pa = prelu_a[0];

    for (int k0 = 0; k0 < K; k0 += BK) {
        #pragma unroll
        for (int t = tid; t < BM * BK / 4; t += 256) {
            int m = t >> 3, kq = t & 7;
            int gm = bm + m;
            float4 v = make_float4(0.f, 0.f, 0.f, 0.f);
            if (gm < M) v = *(const float4*)&A[(size_t)gm * K + k0 + kq * 4];
            if (MODE == 0) {
                v.x = v.x >= 0.f ? v.x : pa * v.x;
                v.y = v.y >= 0.f ? v.y : pa * v.y;
                v.z = v.z >= 0.f ? v.z : pa * v.z;
                v.w = v.w >= 0.f ? v.w : pa * v.w;
            }
            As[kq * 4 + 0][m] = v.x; As[kq * 4 + 1][m] = v.y;
            As[kq * 4 + 2][m] = v.z; As[kq * 4 + 3][m] = v.w;
        }
        #pragma unroll
        for (int t = tid; t < BN * BK / 4; t += 256) {
            int n = t >> 3, kq = t & 7;
            float4 v = *(const float4*)&W[(size_t)(bn + n) * K + k0 + kq * 4];
            Bs[kq * 4 + 0][n] = v.x; Bs[kq * 4 + 1][n] = v.y;
            Bs[kq * 4 + 2][n] = v.z; Bs[kq * 4 + 3][n] = v.w;
        }
        __syncthreads();
        #pragma unroll
        for (int k = 0; k < BK; ++k) {
            float4 a4 = *(const float4*)&As[k][tx * 4];
            float4 b4 = *(const float4*)&Bs[k][ty * 4];
            float av[4] = {a4.x, a4.y, a4.z, a4.w};
            float bv[4] = {b4.x, b4.y, b4.z, b4.w};
            #pragma unroll
            for (int i = 0; i < 4; ++i)
                #pragma unroll
                for (int j = 0; j < 4; ++j)
                    acc[i][j] += av[i] * bv[j];
        }
        __syncthreads();
    }

    const int n0 = bn + ty * 4;
    float se[4];
    if (MODE == 0) {
        #pragma unroll
        for (int j = 0; j < 4; ++j) se[j] = emb1[4 * DD + n0 + j] + emb2[n0 + j];
    }
    #pragma unroll
    for (int i = 0; i < 4; ++i) {
        int gm = bm + tx * 4 + i;
        if (gm >= M) continue;
        if (MODE == 0) {
            ushort4 hb;
            hb.x = f2bf(acc[i][0]); hb.y = f2bf(acc[i][1]);
            hb.z = f2bf(acc[i][2]); hb.w = f2bf(acc[i][3]);
            *(ushort4*)&Hb[(size_t)gm * DD + n0] = hb;
            float4 av = {acc[i][0] + se[0], acc[i][1] + se[1],
                         acc[i][2] + se[2], acc[i][3] + se[3]};
            *(float4*)&Cf[(size_t)gm * NOUT + n0] = av;
        } else {
            float4 v = {acc[i][0] + bias[n0 + 0], acc[i][1] + bias[n0 + 1],
                        acc[i][2] + bias[n0 + 2], acc[i][3] + bias[n0 + 3]};
            if (MODE == 1) {
                v.x = fmaxf(v.x, 0.f); v.y = fmaxf(v.y, 0.f);
                v.z = fmaxf(v.z, 0.f); v.w = fmaxf(v.w, 0.f);
            }
            *(float4*)&Cf[(size_t)gm * NOUT + n0] = v;
        }
    }
}

// ---- CSR build ----

__global__ __launch_bounds__(256) void hist_k(const int* __restrict__ ei,
                                              int* __restrict__ cnt, int E) {
    int e = blockIdx.x * 256 + threadIdx.x;
    if (e < E) atomicAdd(&cnt[ei[E + e]], 1);
}

// per-block (1024 elems) totals
__global__ __launch_bounds__(256) void scan_partial_k(const int* __restrict__ cnt,
                                                      int* __restrict__ bsum, int M) {
    __shared__ int ws[4];
    int base = blockIdx.x * 1024 + threadIdx.x * 4;
    int s = 0;
    #pragma unroll
    for (int i = 0; i < 4; ++i) { int idx = base + i; if (idx < M) s += cnt[idx]; }
    int lane = threadIdx.x & 63, wid = threadIdx.x >> 6;
    int ss = s;
    #pragma unroll
    for (int o = 1; o < 64; o <<= 1) { int t = __shfl_up(ss, o, 64); if (lane >= o) ss += t; }
    if (lane == 63) ws[wid] = ss;
    __syncthreads();
    if (threadIdx.x == 0) bsum[blockIdx.x] = ws[0] + ws[1] + ws[2] + ws[3];
}

// serial exclusive scan of block sums; also writes offs[M] = total
__global__ void scan_bsum_k(int* __restrict__ bsum, int nb, int* __restrict__ offs, int M) {
    if (threadIdx.x == 0 && blockIdx.x == 0) {
        int c = 0;
        for (int i = 0; i < nb; ++i) { int t = bsum[i]; bsum[i] = c; c += t; }
        offs[M] = c;
    }
}

// full exclusive scan -> offs
__global__ __launch_bounds__(256) void scan_final_k(const int* __restrict__ cnt,
                                                    const int* __restrict__ bsum,
                                                    int* __restrict__ offs, int M) {
    __shared__ int ws[4];
    int b = blockIdx.x;
    int base = b * 1024 + threadIdx.x * 4;
    int v[4]; int s = 0;
    #pragma unroll
    for (int i = 0; i < 4; ++i) { int idx = base + i; v[i] = (idx < M) ? cnt[idx] : 0; s += v[i]; }
    int lane = threadIdx.x & 63, wid = threadIdx.x >> 6;
    int ss = s;
    #pragma unroll
    for (int o = 1; o < 64; o <<= 1) { int t = __shfl_up(ss, o, 64); if (lane >= o) ss += t; }
    if (lane == 63) ws[wid] = ss;
    __syncthreads();
    if (threadIdx.x == 0) { int c = 0; for (int w = 0; w < 4; ++w) { int t = ws[w]; ws[w] = c; c += t; } }
    __syncthreads();
    int excl = ss - s + ws[wid] + bsum[b];
    #pragma unroll
    for (int i = 0; i < 4; ++i) {
        int idx = base + i;
        if (idx < M) offs[idx] = excl;
        excl += v[i];
    }
}

__global__ __launch_bounds__(256) void place_k(const int* __restrict__ ei,
                                               const int* __restrict__ ea,
                                               const int* __restrict__ offs,
                                               int* __restrict__ cur,
                                               int* __restrict__ packed, int E) {
    int e = blockIdx.x * 256 + threadIdx.x;
    if (e >= E) return;
    int src = ei[e];
    int dst = ei[E + e];
    int a0 = ea[2 * e], a1 = ea[2 * e + 1];
    int pos = offs[dst] + atomicAdd(&cur[dst], 1);
    packed[pos] = src | ((a0 * 3 + a1) << 20);
}

// per-dst gather-reduce: agg[n] += sum_{edges->n} (h_bf[src] + emb12[combo])
__global__ __launch_bounds__(256) void agg_k(const unsigned short* __restrict__ h,
                                             const int* __restrict__ packed,
                                             const int* __restrict__ offs,
                                             const float* __restrict__ emb1,
                                             const float* __restrict__ emb2,
                                             float* __restrict__ agg, int M) {
    __shared__ float emb12[9][DD];
    for (int t = threadIdx.x; t < 9 * DD; t += 256) {
        int c = t >> 7, col = t & 127;
        emb12[c][col] = emb1[(c / 3) * DD + col] + emb2[(c % 3) * DD + col];
    }
    __syncthreads();
    int n = blockIdx.x * 2 + (threadIdx.x >> 7);
    int col = threadIdx.x & 127;
    if (n >= M) return;
    int beg = offs[n], end = offs[n + 1];
    float acc = agg[(size_t)n * DD + col];
    for (int e = beg; e < end; ++e) {
        int p = packed[e];
        int src = p & 0xFFFFF;
        int combo = p >> 20;
        acc += bf2f(h[(size_t)src * DD + col]) + emb12[combo][col];
    }
    agg[(size_t)n * DD + col] = acc;
}

extern "C" void kernel_launch(void* const* d_in, const int* in_sizes, int n_in,
                              void* d_out, int out_size, void* d_ws, size_t ws_size,
                              hipStream_t stream) {
    const float* x     = (const float*)d_in[0];
    const int*   ei    = (const int*)d_in[1];
    const int*   ea    = (const int*)d_in[2];
    const float* pa    = (const float*)d_in[3];
    const float* Wenc  = (const float*)d_in[4];
    const float* emb1  = (const float*)d_in[5];
    const float* emb2  = (const float*)d_in[6];
    const float* W1    = (const float*)d_in[7];
    const float* b1    = (const float*)d_in[8];
    const float* W2    = (const float*)d_in[9];
    const float* b2    = (const float*)d_in[10];
    float* out = (float*)d_out;

    const int M = in_sizes[0] / DD;
    const int E = in_sizes[1] / 2;

    char* ws = (char*)d_ws;
    size_t o = 0;
    unsigned short* h_bf = (unsigned short*)(ws + o); o += (size_t)M * DD * 2;
    float* agg = (float*)(ws + o); o += (size_t)M * DD * 4;
    float* hid = (float*)(ws + o); o += (size_t)M * DD * 2 * 4;
    int* cnt    = (int*)(ws + o); o += (size_t)M * 4;
    int* cur    = (int*)(ws + o); o += (size_t)M * 4;
    int* offs   = (int*)(ws + o); o += (size_t)(M + 1) * 4;
    int* bsum   = (int*)(ws + o); o += 1024;
    int* packed = (int*)(ws + o); o += (size_t)E * 4;

    const int gm = (M + 63) / 64;
    const int nb = (M + 1023) / 1024;
    dim3 blk(256);

    hipMemsetAsync(cnt, 0, (size_t)M * 4, stream);
    hipMemsetAsync(cur, 0, (size_t)M * 4, stream);

    gemm_k<128, 128, 0><<<dim3(gm, 2), blk, 0, stream>>>(
        x, Wenc, nullptr, agg, h_bf, emb1, emb2, pa, M);

    hist_k<<<dim3((E + 255) / 256), blk, 0, stream>>>(ei, cnt, E);
    scan_partial_k<<<dim3(nb), blk, 0, stream>>>(cnt, bsum, M);
    scan_bsum_k<<<dim3(1), dim3(64), 0, stream>>>(bsum, nb, offs, M);
    scan_final_k<<<dim3(nb), blk, 0, stream>>>(cnt, bsum, offs, M);
    place_k<<<dim3((E + 255) / 256), blk, 0, stream>>>(ei, ea, offs, cur, packed, E);

    agg_k<<<dim3((M + 1) / 2), blk, 0, stream>>>(h_bf, packed, offs, emb1, emb2, agg, M);

    gemm_k<128, 256, 1><<<dim3(gm, 4), blk, 0, stream>>>(
        agg, W1, b1, hid, nullptr, nullptr, nullptr, nullptr, M);

    gemm_k<256, 128, 2><<<dim3(gm, 2), blk, 0, stream>>>(
        hid, W2, b2, out, nullptr, nullptr, nullptr, nullptr, M);
}

// Round 3
// 389.931 us; speedup vs baseline: 7.5066x; 1.8922x over previous
//
#include <hip/hip_runtime.h>
#include <hip/hip_bf16.h>

#define DD 128

typedef short bf16x8 __attribute__((ext_vector_type(8)));
typedef float f32x4 __attribute__((ext_vector_type(4)));

__device__ __forceinline__ float bf2f_lo(unsigned int u) {
    union { unsigned int v; float f; } x; x.v = u << 16; return x.f;
}
__device__ __forceinline__ float bf2f_hi(unsigned int u) {
    union { unsigned int v; float f; } x; x.v = u & 0xFFFF0000u; return x.f;
}
__device__ __forceinline__ unsigned short f2bf(float f) {
    union { float f; unsigned int u; } x; x.f = f;
    unsigned int u = x.u;
    unsigned int r = (u + 0x7FFFu + ((u >> 16) & 1u)) >> 16;  // RNE
    return (unsigned short)r;
}

// ---- MFMA GEMM: C[M x NOUT] = act( A[M x K] @ W[NOUT x K]^T + bias ) ----
// MODE 0: PReLU on A during staging; epilogue: Hb=bf16(acc), Cf=acc+self_emb
// MODE 1: bias + ReLU -> Hb (bf16)
// MODE 2: bias -> Cf (f32)
// ABF: A global is bf16 (ushort) else f32
template<int K, int NOUT, int MODE, bool ABF>
__global__ __launch_bounds__(256) void mgemm_k(
    const void* __restrict__ Ap, const float* __restrict__ W,
    const float* __restrict__ bias, float* __restrict__ Cf,
    unsigned short* __restrict__ Hb,
    const float* __restrict__ emb1, const float* __restrict__ emb2,
    const float* __restrict__ prelu_a, int M)
{
    const int BM = 64, BN = 128, BK = 32;
    __shared__ unsigned short Asl[BM][BK + 8];   // +8 bf16 pad: frag reads 2-way only
    __shared__ unsigned short Bsl[BN][BK + 8];
    const int bm = blockIdx.x * BM;
    const int bn = blockIdx.y * BN;
    const int tid = threadIdx.x;
    const int wid = tid >> 6, lane = tid & 63;
    const int wm = wid >> 1, wn = wid & 1;       // 2x2 waves; wave tile 32(M) x 64(N)
    float pa = (MODE == 0) ? prelu_a[0] : 0.f;

    f32x4 acc[2][4];
    const f32x4 zz = {0.f, 0.f, 0.f, 0.f};
    #pragma unroll
    for (int i = 0; i < 2; ++i)
        #pragma unroll
        for (int j = 0; j < 4; ++j) acc[i][j] = zz;

    for (int k0 = 0; k0 < K; k0 += BK) {
        // stage A: 64 rows x 32 k
        #pragma unroll
        for (int idx = tid; idx < BM * 8; idx += 256) {
            int r = idx >> 3, kq = idx & 7;
            int gr = bm + r; if (gr > M - 1) gr = M - 1;
            ushort4 w;
            if (ABF) {
                w = *(const ushort4*)((const unsigned short*)Ap + (size_t)gr * K + k0 + kq * 4);
            } else {
                float4 v = *(const float4*)((const float*)Ap + (size_t)gr * K + k0 + kq * 4);
                if (MODE == 0) {
                    v.x = v.x >= 0.f ? v.x : pa * v.x;
                    v.y = v.y >= 0.f ? v.y : pa * v.y;
                    v.z = v.z >= 0.f ? v.z : pa * v.z;
                    v.w = v.w >= 0.f ? v.w : pa * v.w;
                }
                w.x = f2bf(v.x); w.y = f2bf(v.y); w.z = f2bf(v.z); w.w = f2bf(v.w);
            }
            *(ushort4*)&Asl[r][kq * 4] = w;
        }
        // stage B (weights, f32): 128 rows x 32 k
        #pragma unroll
        for (int idx = tid; idx < BN * 8; idx += 256) {
            int r = idx >> 3, kq = idx & 7;
            float4 v = *(const float4*)&W[(size_t)(bn + r) * K + k0 + kq * 4];
            ushort4 w;
            w.x = f2bf(v.x); w.y = f2bf(v.y); w.z = f2bf(v.z); w.w = f2bf(v.w);
            *(ushort4*)&Bsl[r][kq * 4] = w;
        }
        __syncthreads();

        const int k8 = (lane >> 4) * 8;
        bf16x8 af[2], bfr[4];
        #pragma unroll
        for (int i = 0; i < 2; ++i)
            af[i] = *(const bf16x8*)&Asl[wm * 32 + i * 16 + (lane & 15)][k8];
        #pragma unroll
        for (int j = 0; j < 4; ++j)
            bfr[j] = *(const bf16x8*)&Bsl[wn * 64 + j * 16 + (lane & 15)][k8];
        #pragma unroll
        for (int i = 0; i < 2; ++i)
            #pragma unroll
            for (int j = 0; j < 4; ++j)
                acc[i][j] = __builtin_amdgcn_mfma_f32_16x16x32_bf16(af[i], bfr[j], acc[i][j], 0, 0, 0);
        __syncthreads();
    }

    // epilogue: D elem (row = (lane>>4)*4 + t, col = lane&15) within each 16x16 frag
    const int rq = (lane >> 4) * 4;
    const int cb = lane & 15;
    #pragma unroll
    for (int i = 0; i < 2; ++i) {
        #pragma unroll
        for (int j = 0; j < 4; ++j) {
            int c = bn + wn * 64 + j * 16 + cb;
            float se = 0.f, bi = 0.f;
            if (MODE == 0) se = emb1[4 * DD + c] + emb2[c];
            if (MODE == 1 || MODE == 2) bi = bias[c];
            int r0 = bm + wm * 32 + i * 16 + rq;
            #pragma unroll
            for (int t = 0; t < 4; ++t) {
                int r = r0 + t;
                if (r >= M) continue;
                float v = acc[i][j][t];
                if (MODE == 0) {
                    Hb[(size_t)r * NOUT + c] = f2bf(v);
                    Cf[(size_t)r * NOUT + c] = v + se;
                } else if (MODE == 1) {
                    v = fmaxf(v + bi, 0.f);
                    Hb[(size_t)r * NOUT + c] = f2bf(v);
                } else {
                    Cf[(size_t)r * NOUT + c] = v + bi;
                }
            }
        }
    }
}

// ---- CSR build ----

__global__ __launch_bounds__(256) void hist_k(const int* __restrict__ ei,
                                              int* __restrict__ cnt, int E) {
    int e = blockIdx.x * 256 + threadIdx.x;
    if (e < E) atomicAdd(&cnt[ei[E + e]], 1);
}

__global__ __launch_bounds__(256) void scan_partial_k(const int* __restrict__ cnt,
                                                      int* __restrict__ bsum, int M) {
    __shared__ int ws[4];
    int base = blockIdx.x * 1024 + threadIdx.x * 4;
    int s = 0;
    #pragma unroll
    for (int i = 0; i < 4; ++i) { int idx = base + i; if (idx < M) s += cnt[idx]; }
    int lane = threadIdx.x & 63, wid = threadIdx.x >> 6;
    int ss = s;
    #pragma unroll
    for (int o = 1; o < 64; o <<= 1) { int t = __shfl_up(ss, o, 64); if (lane >= o) ss += t; }
    if (lane == 63) ws[wid] = ss;
    __syncthreads();
    if (threadIdx.x == 0) bsum[blockIdx.x] = ws[0] + ws[1] + ws[2] + ws[3];
}

__global__ void scan_bsum_k(int* __restrict__ bsum, int nb, int* __restrict__ offs, int M) {
    if (threadIdx.x == 0 && blockIdx.x == 0) {
        int c = 0;
        for (int i = 0; i < nb; ++i) { int t = bsum[i]; bsum[i] = c; c += t; }
        offs[M] = c;
    }
}

__global__ __launch_bounds__(256) void scan_final_k(const int* __restrict__ cnt,
                                                    const int* __restrict__ bsum,
                                                    int* __restrict__ offs, int M) {
    __shared__ int ws[4];
    int b = blockIdx.x;
    int base = b * 1024 + threadIdx.x * 4;
    int v[4]; int s = 0;
    #pragma unroll
    for (int i = 0; i < 4; ++i) { int idx = base + i; v[i] = (idx < M) ? cnt[idx] : 0; s += v[i]; }
    int lane = threadIdx.x & 63, wid = threadIdx.x >> 6;
    int ss = s;
    #pragma unroll
    for (int o = 1; o < 64; o <<= 1) { int t = __shfl_up(ss, o, 64); if (lane >= o) ss += t; }
    if (lane == 63) ws[wid] = ss;
    __syncthreads();
    if (threadIdx.x == 0) { int c = 0; for (int w = 0; w < 4; ++w) { int t = ws[w]; ws[w] = c; c += t; } }
    __syncthreads();
    int excl = ss - s + ws[wid] + bsum[b];
    #pragma unroll
    for (int i = 0; i < 4; ++i) {
        int idx = base + i;
        if (idx < M) offs[idx] = excl;
        excl += v[i];
    }
}

__global__ __launch_bounds__(256) void place_k(const int* __restrict__ ei,
                                               const int* __restrict__ ea,
                                               const int* __restrict__ offs,
                                               int* __restrict__ cur,
                                               int* __restrict__ packed, int E) {
    int e = blockIdx.x * 256 + threadIdx.x;
    if (e >= E) return;
    int src = ei[e];
    int dst = ei[E + e];
    int a0 = ea[2 * e], a1 = ea[2 * e + 1];
    int pos = offs[dst] + atomicAdd(&cur[dst], 1);
    packed[pos] = src | ((a0 * 3 + a1) << 20);
}

// per-dst gather-reduce, one 64-lane wave per row, 4-deep edge unroll
__global__ __launch_bounds__(256) void agg_k(const unsigned short* __restrict__ h,
                                             const int* __restrict__ packed,
                                             const int* __restrict__ offs,
                                             const float* __restrict__ emb1,
                                             const float* __restrict__ emb2,
                                             float* __restrict__ agg, int M) {
    __shared__ float emb12[9][DD];
    for (int t = threadIdx.x; t < 9 * DD; t += 256) {
        int c = t >> 7, col = t & 127;
        emb12[c][col] = emb1[(c / 3) * DD + col] + emb2[(c % 3) * DD + col];
    }
    __syncthreads();
    int wid = threadIdx.x >> 6, lane = threadIdx.x & 63;
    int n = blockIdx.x * 4 + wid;
    if (n >= M) return;
    int c2 = lane * 2;
    int beg = offs[n], end = offs[n + 1];
    float2 acc = *(const float2*)&agg[(size_t)n * DD + c2];
    int e = beg;
    for (; e + 4 <= end; e += 4) {
        int p0 = packed[e + 0], p1 = packed[e + 1];
        int p2 = packed[e + 2], p3 = packed[e + 3];
        unsigned int h0 = *(const unsigned int*)&h[(size_t)(p0 & 0xFFFFF) * DD + c2];
        unsigned int h1 = *(const unsigned int*)&h[(size_t)(p1 & 0xFFFFF) * DD + c2];
        unsigned int h2 = *(const unsigned int*)&h[(size_t)(p2 & 0xFFFFF) * DD + c2];
        unsigned int h3 = *(const unsigned int*)&h[(size_t)(p3 & 0xFFFFF) * DD + c2];
        float2 m0 = *(const float2*)&emb12[p0 >> 20][c2];
        float2 m1 = *(const float2*)&emb12[p1 >> 20][c2];
        float2 m2 = *(const float2*)&emb12[p2 >> 20][c2];
        float2 m3 = *(const float2*)&emb12[p3 >> 20][c2];
        acc.x += (bf2f_lo(h0) + m0.x) + (bf2f_lo(h1) + m1.x)
               + (bf2f_lo(h2) + m2.x) + (bf2f_lo(h3) + m3.x);
        acc.y += (bf2f_hi(h0) + m0.y) + (bf2f_hi(h1) + m1.y)
               + (bf2f_hi(h2) + m2.y) + (bf2f_hi(h3) + m3.y);
    }
    for (; e < end; ++e) {
        int p = packed[e];
        unsigned int hv = *(const unsigned int*)&h[(size_t)(p & 0xFFFFF) * DD + c2];
        float2 m = *(const float2*)&emb12[p >> 20][c2];
        acc.x += bf2f_lo(hv) + m.x;
        acc.y += bf2f_hi(hv) + m.y;
    }
    *(float2*)&agg[(size_t)n * DD + c2] = acc;
}

extern "C" void kernel_launch(void* const* d_in, const int* in_sizes, int n_in,
                              void* d_out, int out_size, void* d_ws, size_t ws_size,
                              hipStream_t stream) {
    const float* x     = (const float*)d_in[0];
    const int*   ei    = (const int*)d_in[1];
    const int*   ea    = (const int*)d_in[2];
    const float* pa    = (const float*)d_in[3];
    const float* Wenc  = (const float*)d_in[4];
    const float* emb1  = (const float*)d_in[5];
    const float* emb2  = (const float*)d_in[6];
    const float* W1    = (const float*)d_in[7];
    const float* b1    = (const float*)d_in[8];
    const float* W2    = (const float*)d_in[9];
    const float* b2    = (const float*)d_in[10];
    float* out = (float*)d_out;

    const int M = in_sizes[0] / DD;
    const int E = in_sizes[1] / 2;

    char* ws = (char*)d_ws;
    size_t o = 0;
    unsigned short* h_bf = (unsigned short*)(ws + o); o += (size_t)M * DD * 2;
    float* agg = (float*)(ws + o); o += (size_t)M * DD * 4;
    unsigned short* hid = (unsigned short*)(ws + o); o += (size_t)M * DD * 2 * 2;
    int* cnt    = (int*)(ws + o); o += (size_t)M * 4;
    int* cur    = (int*)(ws + o); o += (size_t)M * 4;
    int* offs   = (int*)(ws + o); o += (size_t)(M + 1) * 4;
    int* bsum   = (int*)(ws + o); o += 1024;
    int* packed = (int*)(ws + o); o += (size_t)E * 4;

    const int gm = (M + 63) / 64;
    const int nb = (M + 1023) / 1024;
    dim3 blk(256);

    hipMemsetAsync(cnt, 0, (size_t)M * 4, stream);
    hipMemsetAsync(cur, 0, (size_t)M * 4, stream);

    // h = bf16(PReLU(x)) @ bf16(Wenc)^T ; agg = h + self_emb ; h_bf = bf16(h)
    mgemm_k<128, 128, 0, false><<<dim3(gm, 1), blk, 0, stream>>>(
        x, Wenc, nullptr, agg, h_bf, emb1, emb2, pa, M);

    hist_k<<<dim3((E + 255) / 256), blk, 0, stream>>>(ei, cnt, E);
    scan_partial_k<<<dim3(nb), blk, 0, stream>>>(cnt, bsum, M);
    scan_bsum_k<<<dim3(1), dim3(64), 0, stream>>>(bsum, nb, offs, M);
    scan_final_k<<<dim3(nb), blk, 0, stream>>>(cnt, bsum, offs, M);
    place_k<<<dim3((E + 255) / 256), blk, 0, stream>>>(ei, ea, offs, cur, packed, E);

    agg_k<<<dim3((M + 3) / 4), blk, 0, stream>>>(h_bf, packed, offs, emb1, emb2, agg, M);

    // hid = bf16(relu(agg @ W1^T + b1))
    mgemm_k<128, 256, 1, false><<<dim3(gm, 2), blk, 0, stream>>>(
        agg, W1, b1, nullptr, hid, nullptr, nullptr, nullptr, M);

    // out = hid @ W2^T + b2
    mgemm_k<256, 128, 2, true><<<dim3(gm, 1), blk, 0, stream>>>(
        hid, W2, b2, out, nullptr, nullptr, nullptr, nullptr, M);
}

// Round 4
// 302.188 us; speedup vs baseline: 9.6862x; 1.2904x over previous
//
#include <hip/hip_runtime.h>
#include <hip/hip_bf16.h>

#define DD 128

typedef short bf16x8 __attribute__((ext_vector_type(8)));
typedef float f32x4 __attribute__((ext_vector_type(4)));

__device__ __forceinline__ float bf2f_lo(unsigned int u) {
    union { unsigned int v; float f; } x; x.v = u << 16; return x.f;
}
__device__ __forceinline__ float bf2f_hi(unsigned int u) {
    union { unsigned int v; float f; } x; x.v = u & 0xFFFF0000u; return x.f;
}
__device__ __forceinline__ unsigned short f2bf(float f) {
    union { float f; unsigned int u; } x; x.f = f;
    unsigned int u = x.u;
    unsigned int r = (u + 0x7FFFu + ((u >> 16) & 1u)) >> 16;  // RNE
    return (unsigned short)r;
}

// ---- MFMA GEMM: C[M x NOUT] = act( A[M x K] @ W[NOUT x K]^T + bias ) ----
template<int K, int NOUT, int MODE, bool ABF>
__global__ __launch_bounds__(256) void mgemm_k(
    const void* __restrict__ Ap, const float* __restrict__ W,
    const float* __restrict__ bias, float* __restrict__ Cf,
    unsigned short* __restrict__ Hb,
    const float* __restrict__ emb1, const float* __restrict__ emb2,
    const float* __restrict__ prelu_a, int M)
{
    const int BM = 64, BN = 128, BK = 32;
    __shared__ unsigned short Asl[BM][BK + 8];
    __shared__ unsigned short Bsl[BN][BK + 8];
    const int bm = blockIdx.x * BM;
    const int bn = blockIdx.y * BN;
    const int tid = threadIdx.x;
    const int wid = tid >> 6, lane = tid & 63;
    const int wm = wid >> 1, wn = wid & 1;
    float pa = (MODE == 0) ? prelu_a[0] : 0.f;

    f32x4 acc[2][4];
    const f32x4 zz = {0.f, 0.f, 0.f, 0.f};
    #pragma unroll
    for (int i = 0; i < 2; ++i)
        #pragma unroll
        for (int j = 0; j < 4; ++j) acc[i][j] = zz;

    for (int k0 = 0; k0 < K; k0 += BK) {
        #pragma unroll
        for (int idx = tid; idx < BM * 8; idx += 256) {
            int r = idx >> 3, kq = idx & 7;
            int gr = bm + r; if (gr > M - 1) gr = M - 1;
            ushort4 w;
            if (ABF) {
                w = *(const ushort4*)((const unsigned short*)Ap + (size_t)gr * K + k0 + kq * 4);
            } else {
                float4 v = *(const float4*)((const float*)Ap + (size_t)gr * K + k0 + kq * 4);
                if (MODE == 0) {
                    v.x = v.x >= 0.f ? v.x : pa * v.x;
                    v.y = v.y >= 0.f ? v.y : pa * v.y;
                    v.z = v.z >= 0.f ? v.z : pa * v.z;
                    v.w = v.w >= 0.f ? v.w : pa * v.w;
                }
                w.x = f2bf(v.x); w.y = f2bf(v.y); w.z = f2bf(v.z); w.w = f2bf(v.w);
            }
            *(ushort4*)&Asl[r][kq * 4] = w;
        }
        #pragma unroll
        for (int idx = tid; idx < BN * 8; idx += 256) {
            int r = idx >> 3, kq = idx & 7;
            float4 v = *(const float4*)&W[(size_t)(bn + r) * K + k0 + kq * 4];
            ushort4 w;
            w.x = f2bf(v.x); w.y = f2bf(v.y); w.z = f2bf(v.z); w.w = f2bf(v.w);
            *(ushort4*)&Bsl[r][kq * 4] = w;
        }
        __syncthreads();

        const int k8 = (lane >> 4) * 8;
        bf16x8 af[2], bfr[4];
        #pragma unroll
        for (int i = 0; i < 2; ++i)
            af[i] = *(const bf16x8*)&Asl[wm * 32 + i * 16 + (lane & 15)][k8];
        #pragma unroll
        for (int j = 0; j < 4; ++j)
            bfr[j] = *(const bf16x8*)&Bsl[wn * 64 + j * 16 + (lane & 15)][k8];
        #pragma unroll
        for (int i = 0; i < 2; ++i)
            #pragma unroll
            for (int j = 0; j < 4; ++j)
                acc[i][j] = __builtin_amdgcn_mfma_f32_16x16x32_bf16(af[i], bfr[j], acc[i][j], 0, 0, 0);
        __syncthreads();
    }

    const int rq = (lane >> 4) * 4;
    const int cb = lane & 15;
    #pragma unroll
    for (int i = 0; i < 2; ++i) {
        #pragma unroll
        for (int j = 0; j < 4; ++j) {
            int c = bn + wn * 64 + j * 16 + cb;
            float se = 0.f, bi = 0.f;
            if (MODE == 0) se = emb1[4 * DD + c] + emb2[c];
            if (MODE == 1 || MODE == 2) bi = bias[c];
            int r0 = bm + wm * 32 + i * 16 + rq;
            #pragma unroll
            for (int t = 0; t < 4; ++t) {
                int r = r0 + t;
                if (r >= M) continue;
                float v = acc[i][j][t];
                if (MODE == 0) {
                    Hb[(size_t)r * NOUT + c] = f2bf(v);
                    Cf[(size_t)r * NOUT + c] = v + se;
                } else if (MODE == 1) {
                    v = fmaxf(v + bi, 0.f);
                    Hb[(size_t)r * NOUT + c] = f2bf(v);
                } else {
                    Cf[(size_t)r * NOUT + c] = v + bi;
                }
            }
        }
    }
}

// ---- cache-local CSR build ----
// record: src(17) | combo<<17 (4) | dstlocal<<21 (10)

#define SBSH 10          // superbucket = 1024 dst nodes
#define NBP 256          // partition blocks

// A0: per-block superbucket histogram
__global__ __launch_bounds__(256) void sbhist_k(const int* __restrict__ ei,
                                                int* __restrict__ bh,
                                                int E, int chunk, int nsb) {
    __shared__ int h[128];
    for (int i = threadIdx.x; i < nsb; i += 256) h[i] = 0;
    __syncthreads();
    int b = blockIdx.x;
    int beg = b * chunk, end = min(E, beg + chunk);
    for (int e = beg + threadIdx.x; e < end; e += 256)
        atomicAdd(&h[ei[E + e] >> SBSH], 1);
    __syncthreads();
    for (int i = threadIdx.x; i < nsb; i += 256) bh[i * NBP + b] = h[i];
}

// A1: one-block exclusive scan of bh (s-major), plus offs[M]=E
__global__ __launch_bounds__(256) void sbscan_k(const int* __restrict__ bh,
                                                int* __restrict__ bho,
                                                int ntot, int* __restrict__ offs,
                                                int M, int E) {
    __shared__ int ws[4];
    int ch = (ntot + 255) / 256;
    int beg = threadIdx.x * ch, end = min(ntot, beg + ch);
    int s = 0;
    for (int i = beg; i < end; ++i) s += bh[i];
    int lane = threadIdx.x & 63, wid = threadIdx.x >> 6;
    int ss = s;
    #pragma unroll
    for (int o = 1; o < 64; o <<= 1) { int t = __shfl_up(ss, o, 64); if (lane >= o) ss += t; }
    if (lane == 63) ws[wid] = ss;
    __syncthreads();
    if (threadIdx.x == 0) { int c = 0; for (int w = 0; w < 4; ++w) { int t = ws[w]; ws[w] = c; c += t; } }
    __syncthreads();
    int excl = ss - s + ws[wid];
    for (int i = beg; i < end; ++i) { int t = bh[i]; bho[i] = excl; excl += t; }
    if (threadIdx.x == 0) offs[M] = E;
}

// A2: partition records into block-private runs per superbucket
__global__ __launch_bounds__(256) void part_k(const int* __restrict__ ei,
                                              const int* __restrict__ ea,
                                              const int* __restrict__ bho,
                                              int* __restrict__ rec,
                                              int E, int chunk, int nsb) {
    __shared__ int cur[128];
    int b = blockIdx.x;
    for (int i = threadIdx.x; i < nsb; i += 256) cur[i] = bho[i * NBP + b];
    __syncthreads();
    int beg = b * chunk, end = min(E, beg + chunk);
    for (int e = beg + threadIdx.x; e < end; e += 256) {
        int src = ei[e];
        int dst = ei[E + e];
        int a0 = ea[2 * e], a1 = ea[2 * e + 1];
        int pos = atomicAdd(&cur[dst >> SBSH], 1);
        rec[pos] = src | ((a0 * 3 + a1) << 17) | ((dst & 1023) << 21);
    }
}

// B: per-superbucket exact CSR (hist + scan + scatter, all L2/LDS-local)
__global__ __launch_bounds__(1024) void csr_k(const int* __restrict__ rec,
                                              const int* __restrict__ bho,
                                              int* __restrict__ offs,
                                              int* __restrict__ packed,
                                              int nsb, int M, int E) {
    __shared__ int hist[1024];
    __shared__ int lstart[1024];
    __shared__ int wsum[16];
    int s = blockIdx.x;
    int t = threadIdx.x;
    int sb0 = bho[s * NBP];
    int sb1 = (s == nsb - 1) ? E : bho[(s + 1) * NBP];
    hist[t] = 0;
    __syncthreads();
    for (int i = sb0 + t; i < sb1; i += 1024)
        atomicAdd(&hist[(rec[i] >> 21) & 1023], 1);
    __syncthreads();
    int v = hist[t];
    int lane = t & 63, wid = t >> 6;
    int ss = v;
    #pragma unroll
    for (int o = 1; o < 64; o <<= 1) { int u = __shfl_up(ss, o, 64); if (lane >= o) ss += u; }
    if (lane == 63) wsum[wid] = ss;
    __syncthreads();
    if (t == 0) { int c = 0; for (int w = 0; w < 16; ++w) { int x = wsum[w]; wsum[w] = c; c += x; } }
    __syncthreads();
    int excl = ss - v + wsum[wid];
    lstart[t] = excl;
    int node = (s << SBSH) + t;
    if (node < M) offs[node] = sb0 + excl;
    hist[t] = 0;   // reuse as per-dst cursor
    __syncthreads();
    for (int i = sb0 + t; i < sb1; i += 1024) {
        int r = rec[i];
        int dl = (r >> 21) & 1023;
        int pos = sb0 + lstart[dl] + atomicAdd(&hist[dl], 1);
        packed[pos] = r & 0x1FFFFF;
    }
}

// per-dst gather-reduce, one 64-lane wave per row, 4-deep edge unroll
__global__ __launch_bounds__(256) void agg_k(const unsigned short* __restrict__ h,
                                             const int* __restrict__ packed,
                                             const int* __restrict__ offs,
                                             const float* __restrict__ emb1,
                                             const float* __restrict__ emb2,
                                             float* __restrict__ agg, int M) {
    __shared__ float emb12[9][DD];
    for (int t = threadIdx.x; t < 9 * DD; t += 256) {
        int c = t >> 7, col = t & 127;
        emb12[c][col] = emb1[(c / 3) * DD + col] + emb2[(c % 3) * DD + col];
    }
    __syncthreads();
    int wid = threadIdx.x >> 6, lane = threadIdx.x & 63;
    int n = blockIdx.x * 4 + wid;
    if (n >= M) return;
    int c2 = lane * 2;
    int beg = offs[n], end = offs[n + 1];
    float2 acc = *(const float2*)&agg[(size_t)n * DD + c2];
    int e = beg;
    for (; e + 4 <= end; e += 4) {
        int p0 = packed[e + 0], p1 = packed[e + 1];
        int p2 = packed[e + 2], p3 = packed[e + 3];
        unsigned int h0 = *(const unsigned int*)&h[(size_t)(p0 & 0x1FFFF) * DD + c2];
        unsigned int h1 = *(const unsigned int*)&h[(size_t)(p1 & 0x1FFFF) * DD + c2];
        unsigned int h2 = *(const unsigned int*)&h[(size_t)(p2 & 0x1FFFF) * DD + c2];
        unsigned int h3 = *(const unsigned int*)&h[(size_t)(p3 & 0x1FFFF) * DD + c2];
        float2 m0 = *(const float2*)&emb12[(p0 >> 17) & 15][c2];
        float2 m1 = *(const float2*)&emb12[(p1 >> 17) & 15][c2];
        float2 m2 = *(const float2*)&emb12[(p2 >> 17) & 15][c2];
        float2 m3 = *(const float2*)&emb12[(p3 >> 17) & 15][c2];
        acc.x += (bf2f_lo(h0) + m0.x) + (bf2f_lo(h1) + m1.x)
               + (bf2f_lo(h2) + m2.x) + (bf2f_lo(h3) + m3.x);
        acc.y += (bf2f_hi(h0) + m0.y) + (bf2f_hi(h1) + m1.y)
               + (bf2f_hi(h2) + m2.y) + (bf2f_hi(h3) + m3.y);
    }
    for (; e < end; ++e) {
        int p = packed[e];
        unsigned int hv = *(const unsigned int*)&h[(size_t)(p & 0x1FFFF) * DD + c2];
        float2 m = *(const float2*)&emb12[(p >> 17) & 15][c2];
        acc.x += bf2f_lo(hv) + m.x;
        acc.y += bf2f_hi(hv) + m.y;
    }
    *(float2*)&agg[(size_t)n * DD + c2] = acc;
}

extern "C" void kernel_launch(void* const* d_in, const int* in_sizes, int n_in,
                              void* d_out, int out_size, void* d_ws, size_t ws_size,
                              hipStream_t stream) {
    const float* x     = (const float*)d_in[0];
    const int*   ei    = (const int*)d_in[1];
    const int*   ea    = (const int*)d_in[2];
    const float* pa    = (const float*)d_in[3];
    const float* Wenc  = (const float*)d_in[4];
    const float* emb1  = (const float*)d_in[5];
    const float* emb2  = (const float*)d_in[6];
    const float* W1    = (const float*)d_in[7];
    const float* b1    = (const float*)d_in[8];
    const float* W2    = (const float*)d_in[9];
    const float* b2    = (const float*)d_in[10];
    float* out = (float*)d_out;

    const int M = in_sizes[0] / DD;
    const int E = in_sizes[1] / 2;
    const int nsb = (M + 1023) >> SBSH;
    const int chunk = (E + NBP - 1) / NBP;

    char* ws = (char*)d_ws;
    size_t o = 0;
    unsigned short* h_bf = (unsigned short*)(ws + o); o += (size_t)M * DD * 2;
    float* agg = (float*)(ws + o); o += (size_t)M * DD * 4;
    // overlay region: CSR scratch (dead after agg_k) aliased with hid (GEMM2/3)
    char* reg = ws + o;
    unsigned short* hid = (unsigned short*)reg;                 // M*256 bf16 = 51.2 MB
    int* rec    = (int*)reg;                                    // E*4 = 6.4 MB
    int* packed = (int*)(reg + (size_t)E * 4);                  // 6.4 MB
    int* offs   = (int*)(reg + (size_t)E * 8);                  // (M+1)*4
    int* bh     = (int*)(reg + (size_t)E * 8 + (size_t)(M + 1) * 4);
    int* bho    = bh + 128 * NBP;

    const int gm = (M + 63) / 64;
    dim3 blk(256);

    // CSR build (independent of GEMM1)
    sbhist_k<<<dim3(NBP), blk, 0, stream>>>(ei, bh, E, chunk, nsb);
    sbscan_k<<<dim3(1), blk, 0, stream>>>(bh, bho, nsb * NBP, offs, M, E);
    part_k<<<dim3(NBP), blk, 0, stream>>>(ei, ea, bho, rec, E, chunk, nsb);
    csr_k<<<dim3(nsb), dim3(1024), 0, stream>>>(rec, bho, offs, packed, nsb, M, E);

    // h = bf16(PReLU(x)) @ bf16(Wenc)^T ; agg = h + self_emb ; h_bf = bf16(h)
    mgemm_k<128, 128, 0, false><<<dim3(gm, 1), blk, 0, stream>>>(
        x, Wenc, nullptr, agg, h_bf, emb1, emb2, pa, M);

    agg_k<<<dim3((M + 3) / 4), blk, 0, stream>>>(h_bf, packed, offs, emb1, emb2, agg, M);

    // hid = bf16(relu(agg @ W1^T + b1))
    mgemm_k<128, 256, 1, false><<<dim3(gm, 2), blk, 0, stream>>>(
        agg, W1, b1, nullptr, hid, nullptr, nullptr, nullptr, M);

    // out = hid @ W2^T + b2
    mgemm_k<256, 128, 2, true><<<dim3(gm, 1), blk, 0, stream>>>(
        hid, W2, b2, out, nullptr, nullptr, nullptr, nullptr, M);
}

// Round 5
// 261.102 us; speedup vs baseline: 11.2104x; 1.1574x over previous
//
#include <hip/hip_runtime.h>
#include <hip/hip_bf16.h>

#define DD 128

typedef short bf16x8 __attribute__((ext_vector_type(8)));
typedef float f32x4 __attribute__((ext_vector_type(4)));

__device__ __forceinline__ float bf2f_lo(unsigned int u) {
    union { unsigned int v; float f; } x; x.v = u << 16; return x.f;
}
__device__ __forceinline__ float bf2f_hi(unsigned int u) {
    union { unsigned int v; float f; } x; x.v = u & 0xFFFF0000u; return x.f;
}
__device__ __forceinline__ unsigned short f2bf(float f) {
    union { float f; unsigned int u; } x; x.f = f;
    unsigned int u = x.u;
    unsigned int r = (u + 0x7FFFu + ((u >> 16) & 1u)) >> 16;  // RNE
    return (unsigned short)r;
}

// ---- MFMA GEMM: C[M x NOUT] = act( A[M x K] @ W[NOUT x K]^T + bias ) ----
// MODE 0: PReLU on A during staging; epilogue: Hb = bf16(acc) only
// MODE 1: bias + ReLU -> Hb (bf16)
// MODE 2: bias -> Cf (f32)
template<int K, int NOUT, int MODE, bool ABF>
__global__ __launch_bounds__(256) void mgemm_k(
    const void* __restrict__ Ap, const float* __restrict__ W,
    const float* __restrict__ bias, float* __restrict__ Cf,
    unsigned short* __restrict__ Hb,
    const float* __restrict__ prelu_a, int M)
{
    const int BM = 64, BN = 128, BK = 32;
    __shared__ unsigned short Asl[BM][BK + 8];
    __shared__ unsigned short Bsl[BN][BK + 8];
    const int bm = blockIdx.x * BM;
    const int bn = blockIdx.y * BN;
    const int tid = threadIdx.x;
    const int wid = tid >> 6, lane = tid & 63;
    const int wm = wid >> 1, wn = wid & 1;
    float pa = (MODE == 0) ? prelu_a[0] : 0.f;

    f32x4 acc[2][4];
    const f32x4 zz = {0.f, 0.f, 0.f, 0.f};
    #pragma unroll
    for (int i = 0; i < 2; ++i)
        #pragma unroll
        for (int j = 0; j < 4; ++j) acc[i][j] = zz;

    for (int k0 = 0; k0 < K; k0 += BK) {
        #pragma unroll
        for (int idx = tid; idx < BM * 8; idx += 256) {
            int r = idx >> 3, kq = idx & 7;
            int gr = bm + r; if (gr > M - 1) gr = M - 1;
            ushort4 w;
            if (ABF) {
                w = *(const ushort4*)((const unsigned short*)Ap + (size_t)gr * K + k0 + kq * 4);
            } else {
                float4 v = *(const float4*)((const float*)Ap + (size_t)gr * K + k0 + kq * 4);
                if (MODE == 0) {
                    v.x = v.x >= 0.f ? v.x : pa * v.x;
                    v.y = v.y >= 0.f ? v.y : pa * v.y;
                    v.z = v.z >= 0.f ? v.z : pa * v.z;
                    v.w = v.w >= 0.f ? v.w : pa * v.w;
                }
                w.x = f2bf(v.x); w.y = f2bf(v.y); w.z = f2bf(v.z); w.w = f2bf(v.w);
            }
            *(ushort4*)&Asl[r][kq * 4] = w;
        }
        #pragma unroll
        for (int idx = tid; idx < BN * 8; idx += 256) {
            int r = idx >> 3, kq = idx & 7;
            float4 v = *(const float4*)&W[(size_t)(bn + r) * K + k0 + kq * 4];
            ushort4 w;
            w.x = f2bf(v.x); w.y = f2bf(v.y); w.z = f2bf(v.z); w.w = f2bf(v.w);
            *(ushort4*)&Bsl[r][kq * 4] = w;
        }
        __syncthreads();

        const int k8 = (lane >> 4) * 8;
        bf16x8 af[2], bfr[4];
        #pragma unroll
        for (int i = 0; i < 2; ++i)
            af[i] = *(const bf16x8*)&Asl[wm * 32 + i * 16 + (lane & 15)][k8];
        #pragma unroll
        for (int j = 0; j < 4; ++j)
            bfr[j] = *(const bf16x8*)&Bsl[wn * 64 + j * 16 + (lane & 15)][k8];
        #pragma unroll
        for (int i = 0; i < 2; ++i)
            #pragma unroll
            for (int j = 0; j < 4; ++j)
                acc[i][j] = __builtin_amdgcn_mfma_f32_16x16x32_bf16(af[i], bfr[j], acc[i][j], 0, 0, 0);
        __syncthreads();
    }

    const int rq = (lane >> 4) * 4;
    const int cb = lane & 15;
    #pragma unroll
    for (int i = 0; i < 2; ++i) {
        #pragma unroll
        for (int j = 0; j < 4; ++j) {
            int c = bn + wn * 64 + j * 16 + cb;
            float bi = 0.f;
            if (MODE == 1 || MODE == 2) bi = bias[c];
            int r0 = bm + wm * 32 + i * 16 + rq;
            #pragma unroll
            for (int t = 0; t < 4; ++t) {
                int r = r0 + t;
                if (r >= M) continue;
                float v = acc[i][j][t];
                if (MODE == 0) {
                    Hb[(size_t)r * NOUT + c] = f2bf(v);
                } else if (MODE == 1) {
                    v = fmaxf(v + bi, 0.f);
                    Hb[(size_t)r * NOUT + c] = f2bf(v);
                } else {
                    Cf[(size_t)r * NOUT + c] = v + bi;
                }
            }
        }
    }
}

// ---- cache-local CSR build ----
// record: src(17) | combo<<17 (4) | dstlocal<<21 (10)

#define SBSH 10
#define NBP 256

__global__ __launch_bounds__(256) void sbhist_k(const int* __restrict__ ei,
                                                int* __restrict__ bh,
                                                int E, int chunk, int nsb) {
    __shared__ int h4[4][128];
    int wid = threadIdx.x >> 6;
    for (int i = threadIdx.x; i < 4 * 128; i += 256) ((int*)h4)[i] = 0;
    __syncthreads();
    int b = blockIdx.x;
    int beg = b * chunk, end = min(E, beg + chunk);
    for (int e = beg + threadIdx.x; e < end; e += 256)
        atomicAdd(&h4[wid][ei[E + e] >> SBSH], 1);
    __syncthreads();
    for (int i = threadIdx.x; i < nsb; i += 256)
        bh[i * NBP + b] = h4[0][i] + h4[1][i] + h4[2][i] + h4[3][i];
}

__global__ __launch_bounds__(256) void sbscan_k(const int* __restrict__ bh,
                                                int* __restrict__ bho,
                                                int ntot, int* __restrict__ offs,
                                                int M, int E) {
    __shared__ int ws[4];
    int ch = (ntot + 255) / 256;
    int beg = threadIdx.x * ch, end = min(ntot, beg + ch);
    int s = 0;
    for (int i = beg; i < end; ++i) s += bh[i];
    int lane = threadIdx.x & 63, wid = threadIdx.x >> 6;
    int ss = s;
    #pragma unroll
    for (int o = 1; o < 64; o <<= 1) { int t = __shfl_up(ss, o, 64); if (lane >= o) ss += t; }
    if (lane == 63) ws[wid] = ss;
    __syncthreads();
    if (threadIdx.x == 0) { int c = 0; for (int w = 0; w < 4; ++w) { int t = ws[w]; ws[w] = c; c += t; } }
    __syncthreads();
    int excl = ss - s + ws[wid];
    for (int i = beg; i < end; ++i) { int t = bh[i]; bho[i] = excl; excl += t; }
    if (threadIdx.x == 0) offs[M] = E;
}

__global__ __launch_bounds__(256) void part_k(const int* __restrict__ ei,
                                              const int* __restrict__ ea,
                                              const int* __restrict__ bho,
                                              int* __restrict__ rec,
                                              int E, int chunk, int nsb) {
    __shared__ int cur[128];
    int b = blockIdx.x;
    for (int i = threadIdx.x; i < nsb; i += 256) cur[i] = bho[i * NBP + b];
    __syncthreads();
    int beg = b * chunk, end = min(E, beg + chunk);
    for (int e = beg + threadIdx.x; e < end; e += 256) {
        int src = ei[e];
        int dst = ei[E + e];
        int a0 = ea[2 * e], a1 = ea[2 * e + 1];
        int pos = atomicAdd(&cur[dst >> SBSH], 1);
        rec[pos] = src | ((a0 * 3 + a1) << 17) | ((dst & 1023) << 21);
    }
}

__global__ __launch_bounds__(1024) void csr_k(const int* __restrict__ rec,
                                              const int* __restrict__ bho,
                                              int* __restrict__ offs,
                                              int* __restrict__ packed,
                                              int nsb, int M, int E) {
    __shared__ int hist[1024];
    __shared__ int lstart[1024];
    __shared__ int wsum[16];
    int s = blockIdx.x;
    int t = threadIdx.x;
    int sb0 = bho[s * NBP];
    int sb1 = (s == nsb - 1) ? E : bho[(s + 1) * NBP];
    hist[t] = 0;
    __syncthreads();
    for (int i = sb0 + t; i < sb1; i += 1024)
        atomicAdd(&hist[(rec[i] >> 21) & 1023], 1);
    __syncthreads();
    int v = hist[t];
    int lane = t & 63, wid = t >> 6;
    int ss = v;
    #pragma unroll
    for (int o = 1; o < 64; o <<= 1) { int u = __shfl_up(ss, o, 64); if (lane >= o) ss += u; }
    if (lane == 63) wsum[wid] = ss;
    __syncthreads();
    if (t == 0) { int c = 0; for (int w = 0; w < 16; ++w) { int x = wsum[w]; wsum[w] = c; c += x; } }
    __syncthreads();
    int excl = ss - v + wsum[wid];
    lstart[t] = excl;
    int node = (s << SBSH) + t;
    if (node < M) offs[node] = sb0 + excl;
    hist[t] = 0;
    __syncthreads();
    for (int i = sb0 + t; i < sb1; i += 1024) {
        int r = rec[i];
        int dl = (r >> 21) & 1023;
        int pos = sb0 + lstart[dl] + atomicAdd(&hist[dl], 1);
        packed[pos] = r & 0x1FFFFF;
    }
}

// per-dst gather-reduce: aggb[n] = bf16( h[n] + self_emb + sum_e (h[src]+emb12[combo]) )
__global__ __launch_bounds__(256) void agg_k(const unsigned short* __restrict__ h,
                                             const int* __restrict__ packed,
                                             const int* __restrict__ offs,
                                             const float* __restrict__ emb1,
                                             const float* __restrict__ emb2,
                                             unsigned int* __restrict__ aggb, int M) {
    __shared__ float emb12[10][DD];
    for (int t = threadIdx.x; t < 10 * DD; t += 256) {
        int c = t >> 7, col = t & 127;
        float v;
        if (c == 9) v = emb1[4 * DD + col] + emb2[col];          // self-loop emb
        else        v = emb1[(c / 3) * DD + col] + emb2[(c % 3) * DD + col];
        emb12[c][col] = v;
    }
    __syncthreads();
    int wid = threadIdx.x >> 6, lane = threadIdx.x & 63;
    int n = blockIdx.x * 4 + wid;
    if (n >= M) return;
    n = __builtin_amdgcn_readfirstlane(n);      // wave-uniform -> scalar addressing
    int c2 = lane * 2;
    int beg = offs[n], end = offs[n + 1];
    unsigned int hn = *(const unsigned int*)&h[(size_t)n * DD + c2];
    float2 se = *(const float2*)&emb12[9][c2];
    float2 acc = {bf2f_lo(hn) + se.x, bf2f_hi(hn) + se.y};
    int e = beg;
    for (; e + 8 <= end; e += 8) {
        int p[8]; unsigned int hv[8]; float2 m[8];
        #pragma unroll
        for (int i = 0; i < 8; ++i) p[i] = packed[e + i];
        #pragma unroll
        for (int i = 0; i < 8; ++i)
            hv[i] = *(const unsigned int*)&h[(size_t)(p[i] & 0x1FFFF) * DD + c2];
        #pragma unroll
        for (int i = 0; i < 8; ++i)
            m[i] = *(const float2*)&emb12[(p[i] >> 17) & 15][c2];
        #pragma unroll
        for (int i = 0; i < 8; ++i) {
            acc.x += bf2f_lo(hv[i]) + m[i].x;
            acc.y += bf2f_hi(hv[i]) + m[i].y;
        }
    }
    if (e + 4 <= end) {
        int p[4]; unsigned int hv[4]; float2 m[4];
        #pragma unroll
        for (int i = 0; i < 4; ++i) p[i] = packed[e + i];
        #pragma unroll
        for (int i = 0; i < 4; ++i)
            hv[i] = *(const unsigned int*)&h[(size_t)(p[i] & 0x1FFFF) * DD + c2];
        #pragma unroll
        for (int i = 0; i < 4; ++i)
            m[i] = *(const float2*)&emb12[(p[i] >> 17) & 15][c2];
        #pragma unroll
        for (int i = 0; i < 4; ++i) {
            acc.x += bf2f_lo(hv[i]) + m[i].x;
            acc.y += bf2f_hi(hv[i]) + m[i].y;
        }
        e += 4;
    }
    for (; e < end; ++e) {
        int p = packed[e];
        unsigned int hv = *(const unsigned int*)&h[(size_t)(p & 0x1FFFF) * DD + c2];
        float2 m = *(const float2*)&emb12[(p >> 17) & 15][c2];
        acc.x += bf2f_lo(hv) + m.x;
        acc.y += bf2f_hi(hv) + m.y;
    }
    aggb[((size_t)n * DD + c2) >> 1] = ((unsigned int)f2bf(acc.y) << 16) | f2bf(acc.x);
}

extern "C" void kernel_launch(void* const* d_in, const int* in_sizes, int n_in,
                              void* d_out, int out_size, void* d_ws, size_t ws_size,
                              hipStream_t stream) {
    const float* x     = (const float*)d_in[0];
    const int*   ei    = (const int*)d_in[1];
    const int*   ea    = (const int*)d_in[2];
    const float* pa    = (const float*)d_in[3];
    const float* Wenc  = (const float*)d_in[4];
    const float* emb1  = (const float*)d_in[5];
    const float* emb2  = (const float*)d_in[6];
    const float* W1    = (const float*)d_in[7];
    const float* b1    = (const float*)d_in[8];
    const float* W2    = (const float*)d_in[9];
    const float* b2    = (const float*)d_in[10];
    float* out = (float*)d_out;

    const int M = in_sizes[0] / DD;
    const int E = in_sizes[1] / 2;
    const int nsb = (M + 1023) >> SBSH;
    const int chunk = (E + NBP - 1) / NBP;

    char* ws = (char*)d_ws;
    size_t o = 0;
    unsigned short* h_bf  = (unsigned short*)(ws + o); o += (size_t)M * DD * 2;
    unsigned int*   aggb  = (unsigned int*)(ws + o);   o += (size_t)M * DD * 2;
    // overlay: CSR scratch (dead after agg_k) aliased with hid (written by GEMM2)
    char* reg = ws + o;
    unsigned short* hid = (unsigned short*)reg;                 // M*256 bf16
    int* rec    = (int*)reg;
    int* packed = (int*)(reg + (size_t)E * 4);
    int* offs   = (int*)(reg + (size_t)E * 8);
    int* bh     = (int*)(reg + (size_t)E * 8 + (size_t)(M + 1) * 4);
    int* bho    = bh + 128 * NBP;

    const int gm = (M + 63) / 64;
    dim3 blk(256);

    sbhist_k<<<dim3(NBP), blk, 0, stream>>>(ei, bh, E, chunk, nsb);
    sbscan_k<<<dim3(1), blk, 0, stream>>>(bh, bho, nsb * NBP, offs, M, E);
    part_k<<<dim3(NBP), blk, 0, stream>>>(ei, ea, bho, rec, E, chunk, nsb);
    csr_k<<<dim3(nsb), dim3(1024), 0, stream>>>(rec, bho, offs, packed, nsb, M, E);

    // h_bf = bf16( PReLU(x) @ Wenc^T )
    mgemm_k<128, 128, 0, false><<<dim3(gm, 1), blk, 0, stream>>>(
        x, Wenc, nullptr, nullptr, h_bf, pa, M);

    agg_k<<<dim3((M + 3) / 4), blk, 0, stream>>>(h_bf, packed, offs, emb1, emb2, aggb, M);

    // hid = bf16(relu(aggb @ W1^T + b1))
    mgemm_k<128, 256, 1, true><<<dim3(gm, 2), blk, 0, stream>>>(
        aggb, W1, b1, nullptr, hid, nullptr, M);

    // out = hid @ W2^T + b2
    mgemm_k<256, 128, 2, true><<<dim3(gm, 1), blk, 0, stream>>>(
        hid, W2, b2, out, nullptr, nullptr, M);
}